// Round 5
// baseline (571.229 us; speedup 1.0000x reference)
//
#include <hip/hip_runtime.h>

// BatchedHGNNLayer: out = [Dv^-1/2 H De^-1 H^T Dv^-1/2 x] W^T + b
// B=8, N=4096, E=2048, C=128.
// R8: st1 + De-machinery elimination.
//   k0_prep: zero cnt[128] + pre-swizzled bf16 W. (De array gone.)
//   k1_fused: H fp32 -> Hbf bf16 + Dv + xsT transpose. De work removed
//     (no Lde, no dc[8], no atomics) -> leaner stream kernel.
//   gemm1_fused: K-loop unchanged (3-buf, counted vmcnt(2), XCD remap).
//     NEW: writeB also accumulates per-e-column De partials from the very
//     registers holding Hbf (guarded vs clamped dup of tile 31); epilogue
//     writes P partial + Pde partial, threadfence, counter atomicAdd; the
//     LAST block of each (b,et) quad sums 4 P partials + 4 De partials
//     (L2-hot, same XCD), divides, writes out2T bf16. st1 dispatch gone.
//   gemm2_fused: unchanged R7 (M-tile 64, 2 blk/CU, fused linear epilogue).
// ws: Hbf 128MiB | xsT 8MiB | out2T 4MiB | P 32MiB | Wsw 32KiB | Pde 256KiB
//     | cnt 512B | Dv 128KiB

#define EPS 1e-6f
constexpr int B_ = 8, N_ = 4096, E_ = 2048, C_ = 128;

typedef __bf16 bf16x8 __attribute__((ext_vector_type(8)));
typedef float f32x4 __attribute__((ext_vector_type(4)));

__device__ __forceinline__ unsigned int f2bf_pack(float lo, float hi) {
  unsigned int ul = __float_as_uint(lo), uh = __float_as_uint(hi);
  ul = (ul + 0x7fffu + ((ul >> 16) & 1u)) >> 16;
  uh = (uh + 0x7fffu + ((uh >> 16) & 1u)) & 0xffff0000u;
  return uh | ul;
}

__device__ __forceinline__ unsigned short f2bf1(float x) {
  unsigned int u = __float_as_uint(x);
  return (unsigned short)((u + 0x7fffu + ((u >> 16) & 1u)) >> 16);
}

__device__ __forceinline__ void gl2lds16(const void* g, void* l) {
  __builtin_amdgcn_global_load_lds(
      (const __attribute__((address_space(1))) void*)g,
      (__attribute__((address_space(3))) void*)l, 16, 0, 0);
}

// ---------------------------------------------------------------------------
// k0_prep: cnt = 0; Wsw[row][col ^ ((row&7)<<3)] = bf16(W[row][col]).
__global__ __launch_bounds__(256) void k0_prep(
    const float* __restrict__ W, unsigned short* __restrict__ Wsw,
    unsigned int* __restrict__ cnt) {
  const int i4 = (blockIdx.x * 256 + threadIdx.x) * 4;
  if (blockIdx.x == 0 && threadIdx.x < 32)
    *(uint4*)(cnt + threadIdx.x * 4) = make_uint4(0u, 0u, 0u, 0u);
  const int row = i4 >> 7, col = i4 & 127;
  const f32x4 v = *(const f32x4*)(W + i4);
  uint2 p;
  p.x = f2bf_pack(v[0], v[1]);
  p.y = f2bf_pack(v[2], v[3]);
  *(uint2*)(Wsw + row * 128 + (col ^ ((row & 7) << 3))) = p;
}

// ---------------------------------------------------------------------------
// K1: per 64-row slab: stream H fp32 -> Hbf bf16; Dv row sums (global + Ldv);
// then xsT[c][n] = bf16(x[n][c] * rsqrt(Dv)) via LDS transpose. No De work.
__global__ __launch_bounds__(256) void k1_fused(
    const float* __restrict__ H, const float* __restrict__ x,
    unsigned short* __restrict__ Hbf, unsigned short* __restrict__ xsT,
    float* __restrict__ Dv) {
  __shared__ float Ldv[64];
  __shared__ unsigned int T[128][33];  // [col c][row pair], bf16-pair packed
  const int t = threadIdx.x;
  const int w = t >> 6, l = t & 63;
  const size_t row0 = (size_t)blockIdx.x * 64;
  const int b = (int)(row0 >> 12);  // N_ = 4096
  for (int i = 0; i < 16; ++i) {
    const size_t r = row0 + w * 16 + i;
    const float* src = H + r * E_;
    unsigned short* dst = Hbf + r * E_;
    float rs = 0.f;
#pragma unroll
    for (int j = 0; j < 8; ++j) {
      const f32x4 v = *(const f32x4*)(src + 256 * j + 4 * l);
      rs += v[0] + v[1] + v[2] + v[3];
      uint2 p;
      p.x = f2bf_pack(v[0], v[1]);
      p.y = f2bf_pack(v[2], v[3]);
      *(uint2*)(dst + 256 * j + 4 * l) = p;
    }
#pragma unroll
    for (int o = 32; o; o >>= 1) rs += __shfl_xor(rs, o);
    if (l == 0) {
      Dv[r] = rs;
      Ldv[w * 16 + i] = rs;
    }
  }
  __syncthreads();
  // st0 phase 1: rows 2p,2p+1 scaled+packed into T[col][p].
  {
    const int p = t >> 3, cq = t & 7;
    const float s0 = 1.f / sqrtf(Ldv[2 * p] + EPS);
    const float s1 = 1.f / sqrtf(Ldv[2 * p + 1] + EPS);
    const float* r0p = x + (row0 + 2 * p) * 128;
    const float* r1p = r0p + 128;
#pragma unroll
    for (int i = 0; i < 4; ++i) {
      const int c = 32 * i + 4 * cq;
      const f32x4 a = *(const f32x4*)(r0p + c);
      const f32x4 b2 = *(const f32x4*)(r1p + c);
#pragma unroll
      for (int j = 0; j < 4; ++j) T[c + j][p] = f2bf_pack(a[j] * s0, b2[j] * s1);
    }
  }
  __syncthreads();
  // Phase 2: write xsT[c][n0..n0+63], 64B per thread.
  {
    const int crow = t >> 1, h = t & 1;
    const int nb = (int)(row0 & (N_ - 1));
    unsigned int u[16];
#pragma unroll
    for (int i = 0; i < 16; ++i) u[i] = T[crow][h * 16 + i];
    uint4* dst = (uint4*)(xsT + (size_t)b * C_ * N_ + (size_t)crow * N_ + nb + h * 32);
#pragma unroll
    for (int i = 0; i < 4; ++i)
      dst[i] = make_uint4(u[4 * i], u[4 * i + 1], u[4 * i + 2], u[4 * i + 3]);
  }
}

// ---------------------------------------------------------------------------
// writeB: transpose-pack one B reg-tile into LDS; optionally accumulate the
// per-e-column De partials (accum=false for the clamped duplicate tile).
__device__ __forceinline__ void writeB(unsigned short* dst, uint4 PL, uint4 PH,
                                       int q, int bwo, float* des, bool accum) {
  unsigned int wl[4] = {PL.x, PL.y, PL.z, PL.w};
  unsigned int wh[4] = {PH.x, PH.y, PH.z, PH.w};
#pragma unroll
  for (int j = 0; j < 8; ++j) {
    const unsigned int lo16 = (wl[j >> 1] >> (16 * (j & 1))) & 0xffffu;
    const unsigned int hi16 = (wh[j >> 1] >> (16 * (j & 1))) & 0xffffu;
    *(unsigned int*)(dst + (8 * q + j) * 40 + bwo) = lo16 | (hi16 << 16);
    if (accum)
      des[j] += __uint_as_float(lo16 << 16) + __uint_as_float(hi16 << 16);
  }
}

// gemm1_fused: P_sk[b][c][e] = sum_{n in split} xsT[c][n] * Hbf[n][e],
// De partials from writeB regs, counter-gated last-block reduction writes
// out2T[b][c][e] = bf16(sum_s P_s / (De+eps)). grid (E/128, 4, B), XCD remap.
__global__ __launch_bounds__(256) void gemm1_fused(
    const unsigned short* __restrict__ Hbf, const unsigned short* __restrict__ xsT,
    float* __restrict__ P, float* __restrict__ Pde, unsigned int* __restrict__ cnt,
    unsigned short* __restrict__ out2T) {
  __shared__ unsigned short Als[3][128 * 32];
  __shared__ unsigned short Bls[3][128 * 40];
  __shared__ unsigned int sflag;
  const int t = threadIdx.x;
  const int w = t >> 6, l = t & 63;
  const int lin = blockIdx.x + 16 * blockIdx.y + 64 * blockIdx.z;  // [0,512)
  const int wg = (lin & 7) * 64 + (lin >> 3);
  const int et = wg & 15, sk = (wg >> 4) & 3, b = wg >> 6;
  const int k0 = sk * (N_ / 4);
  const int e0 = et * 128;
  const unsigned short* Ab = xsT + (size_t)b * C_ * N_ + k0;
  const int srow = l >> 2, scol = (l & 3) * 8;
  const unsigned short* ga0 = Ab + (size_t)(w * 32 + srow) * N_ + scol;
  const unsigned short* ga1 = ga0 + (size_t)16 * N_;
  const int la0 = (w * 32) * 32;
  const int la1 = (w * 32 + 16) * 32;
  const int np = t >> 4, q = t & 15;
  const int bwo = (2 * np) ^ ((q & 3) << 3);
  const unsigned short* gb =
      Hbf + (size_t)b * N_ * E_ + (size_t)(k0 + 2 * np) * E_ + e0 + 8 * q;
  const int mrow = (w & 1) * 64, ncol = (w >> 1) * 64;
  const int fr = l & 15, fq = l >> 4;
  f32x4 acc[4][4];
#pragma unroll
  for (int i = 0; i < 4; ++i)
#pragma unroll
    for (int j = 0; j < 4; ++j) acc[i][j] = (f32x4){0.f, 0.f, 0.f, 0.f};
  float des[8];
#pragma unroll
  for (int j = 0; j < 8; ++j) des[j] = 0.f;
  constexpr int nsteps = (N_ / 4) / 32;  // 32 (even)

  unsigned short *A0 = &Als[0][0], *A1 = &Als[1][0], *A2 = &Als[2][0];
  unsigned short *B0 = &Bls[0][0], *B1 = &Bls[1][0], *B2 = &Bls[2][0];

  uint4 pl0 = *(const uint4*)gb;
  uint4 ph0 = *(const uint4*)(gb + E_);
  gl2lds16(ga0, A0 + la0);
  gl2lds16(ga1, A0 + la1);
  uint4 pl1 = *(const uint4*)(gb + (size_t)32 * E_);
  uint4 ph1 = *(const uint4*)(gb + (size_t)33 * E_);
  gl2lds16(ga0 + 32, A1 + la0);
  gl2lds16(ga1 + 32, A1 + la1);
  asm volatile("s_waitcnt vmcnt(6)" ::: "memory");
  writeB(B0, pl0, ph0, q, bwo, des, true);  // tile 0

  for (int kt = 0; kt < nsteps; kt += 2) {
    {  // even sub-iter: compute tile kt; write tile kt+1 (always valid)
      asm volatile("s_waitcnt vmcnt(2) lgkmcnt(0)" ::: "memory");
      __builtin_amdgcn_s_barrier();
      asm volatile("" ::: "memory");
      writeB(B1, pl1, ph1, q, bwo, des, true);
      const int tc = (kt + 2 < nsteps) ? kt + 2 : nsteps - 1;
      const unsigned short* g2 = gb + (size_t)tc * 32 * E_;
      pl0 = *(const uint4*)g2;
      ph0 = *(const uint4*)(g2 + E_);
      gl2lds16(ga0 + tc * 32, A2 + la0);
      gl2lds16(ga1 + tc * 32, A2 + la1);
      bf16x8 af[4], bfr[4];
#pragma unroll
      for (int i = 0; i < 4; ++i) {
        af[i] = *(const bf16x8*)(A0 + (mrow + i * 16 + fr) * 32 + fq * 8);
        const int brow = ncol + i * 16 + fr;
        const int nsw = (fq * 8) ^ (((brow >> 3) & 3) << 3);
        bfr[i] = *(const bf16x8*)(B0 + brow * 40 + nsw);
      }
#pragma unroll
      for (int i = 0; i < 4; ++i)
#pragma unroll
        for (int j = 0; j < 4; ++j)
          acc[i][j] = __builtin_amdgcn_mfma_f32_16x16x32_bf16(af[i], bfr[j],
                                                              acc[i][j], 0, 0, 0);
      unsigned short* x0 = A0; A0 = A1; A1 = A2; A2 = x0;
      unsigned short* y0 = B0; B0 = B1; B1 = B2; B2 = y0;
    }
    {  // odd sub-iter: compute tile kt+1; write tile kt+2 (dup-guarded)
      asm volatile("s_waitcnt vmcnt(2) lgkmcnt(0)" ::: "memory");
      __builtin_amdgcn_s_barrier();
      asm volatile("" ::: "memory");
      writeB(B1, pl0, ph0, q, bwo, des, kt + 2 < nsteps);
      const int tc = (kt + 3 < nsteps) ? kt + 3 : nsteps - 1;
      const unsigned short* g2 = gb + (size_t)tc * 32 * E_;
      pl1 = *(const uint4*)g2;
      ph1 = *(const uint4*)(g2 + E_);
      gl2lds16(ga0 + tc * 32, A2 + la0);
      gl2lds16(ga1 + tc * 32, A2 + la1);
      bf16x8 af[4], bfr[4];
#pragma unroll
      for (int i = 0; i < 4; ++i) {
        af[i] = *(const bf16x8*)(A0 + (mrow + i * 16 + fr) * 32 + fq * 8);
        const int brow = ncol + i * 16 + fr;
        const int nsw = (fq * 8) ^ (((brow >> 3) & 3) << 3);
        bfr[i] = *(const bf16x8*)(B0 + brow * 40 + nsw);
      }
#pragma unroll
      for (int i = 0; i < 4; ++i)
#pragma unroll
        for (int j = 0; j < 4; ++j)
          acc[i][j] = __builtin_amdgcn_mfma_f32_16x16x32_bf16(af[i], bfr[j],
                                                              acc[i][j], 0, 0, 0);
      unsigned short* x0 = A0; A0 = A1; A1 = A2; A2 = x0;
      unsigned short* y0 = B0; B0 = B1; B1 = B2; B2 = y0;
    }
  }
  // Drain in-flight gl2lds (LDS reuse + retire hazard), then reuse Bls[0].
  asm volatile("s_waitcnt vmcnt(0) lgkmcnt(0)" ::: "memory");
  __syncthreads();
  // np-reduce of De partials: Lde2[np][e-col] -> Pde[sk][b][et][128].
  float* Lde2 = (float*)&Bls[0][0];  // 8 KiB
  *(f32x4*)&Lde2[np * 128 + 8 * q] = (f32x4){des[0], des[1], des[2], des[3]};
  *(f32x4*)&Lde2[np * 128 + 8 * q + 4] = (f32x4){des[4], des[5], des[6], des[7]};
  __syncthreads();
  if (t < 128) {
    float s = 0.f;
#pragma unroll
    for (int i2 = 0; i2 < 16; ++i2) s += Lde2[i2 * 128 + t];
    Pde[(((size_t)sk * B_ + b) * 16 + et) * 128 + t] = s;
  }
  // P partial store.
  float* Pb = P + (((size_t)sk * B_ + b) * C_) * E_ + e0;
#pragma unroll
  for (int i = 0; i < 4; ++i)
#pragma unroll
    for (int j = 0; j < 4; ++j)
#pragma unroll
      for (int r = 0; r < 4; ++r) {
        const int row = mrow + i * 16 + fq * 4 + r;  // C/D: col=lane&15
        const int col = ncol + j * 16 + fr;
        Pb[(size_t)row * E_ + col] = acc[i][j][r];
      }
  __threadfence();
  __syncthreads();
  if (t == 0) sflag = atomicAdd(&cnt[b * 16 + et], 1u);
  __syncthreads();
  if (sflag == 3u) {
    // Last block of this (b,et) quad: all 4 partials visible (same XCD).
    __threadfence();
    if (t < 128) {
      float s = EPS;
#pragma unroll
      for (int s4 = 0; s4 < 4; ++s4)
        s += Pde[(((size_t)s4 * B_ + b) * 16 + et) * 128 + t];
      Lde2[t] = 1.f / s;
    }
    __syncthreads();
    const int row = t >> 1, c0 = (t & 1) * 64;
    unsigned short* od = out2T + (size_t)b * C_ * E_ + (size_t)row * E_ + e0 + c0;
#pragma unroll
    for (int ch = 0; ch < 4; ++ch) {
      f32x4 a0 = (f32x4){0.f, 0.f, 0.f, 0.f}, a1 = a0, a2 = a0, a3 = a0;
#pragma unroll
      for (int s4 = 0; s4 < 4; ++s4) {
        const float* p = P + ((size_t)s4 * B_ + b) * C_ * E_ + (size_t)row * E_ +
                         e0 + c0 + ch * 16;
        a0 += *(const f32x4*)(p);
        a1 += *(const f32x4*)(p + 4);
        a2 += *(const f32x4*)(p + 8);
        a3 += *(const f32x4*)(p + 12);
      }
      const f32x4 d0 = *(const f32x4*)&Lde2[c0 + ch * 16];
      const f32x4 d1 = *(const f32x4*)&Lde2[c0 + ch * 16 + 4];
      const f32x4 d2 = *(const f32x4*)&Lde2[c0 + ch * 16 + 8];
      const f32x4 d3 = *(const f32x4*)&Lde2[c0 + ch * 16 + 12];
      uint4 o1, o2;
      o1.x = f2bf_pack(a0[0] * d0[0], a0[1] * d0[1]);
      o1.y = f2bf_pack(a0[2] * d0[2], a0[3] * d0[3]);
      o1.z = f2bf_pack(a1[0] * d1[0], a1[1] * d1[1]);
      o1.w = f2bf_pack(a1[2] * d1[2], a1[3] * d1[3]);
      o2.x = f2bf_pack(a2[0] * d2[0], a2[1] * d2[1]);
      o2.y = f2bf_pack(a2[2] * d2[2], a2[3] * d2[3]);
      o2.z = f2bf_pack(a3[0] * d3[0], a3[1] * d3[1]);
      o2.w = f2bf_pack(a3[2] * d3[2], a3[3] * d3[3]);
      *(uint4*)(od + ch * 16) = o1;
      *(uint4*)(od + ch * 16 + 8) = o2;
    }
  }
}

// ---------------------------------------------------------------------------
// gemm2_fused: Q[b][n][c] = sum_e Hbf[n][e]*out2T[c][e] (FULL K), M-tile 64,
// then out = bf16(Q * rsqrt(Dv)) @ Wsw^T + bias. grid (N/64, 1, B) = 512
// blocks (2/CU). 3-buffer, counted vmcnt(3). Waves split the C dimension.
__global__ __launch_bounds__(256) void gemm2_fused(
    const unsigned short* __restrict__ Hbf, const unsigned short* __restrict__ out2T,
    const unsigned short* __restrict__ Wsw, const float* __restrict__ bias,
    const float* __restrict__ Dv, float* __restrict__ out) {
  __shared__ unsigned short LDS[24576];  // 48 KiB
  const int t = threadIdx.x;
  const int w = t >> 6, l = t & 63;
  const int lin = blockIdx.x + 64 * blockIdx.z;  // [0,512)
  const int wg = (lin & 7) * 64 + (lin >> 3);
  const int mt = wg & 63, b = wg >> 6;
  const int n0 = mt * 64;
  const unsigned short* Ab = Hbf + ((size_t)b * N_ + n0) * E_;
  const unsigned short* Btb = out2T + (size_t)b * C_ * E_;
  const int srow = l >> 2, scol = (l & 3) * 8;
  const unsigned short* ga0 = Ab + (size_t)(w * 16 + srow) * E_ + scol;
  const unsigned short* gb0 = Btb + (size_t)(w * 32 + srow) * E_ + scol;
  const unsigned short* gb1 = gb0 + (size_t)16 * E_;
  const int la0 = w * 512;
  const int lb0 = w * 1024, lb1 = w * 1024 + 512;
  unsigned short *A0 = LDS, *A1 = LDS + 2048, *A2 = LDS + 4096;
  unsigned short *B0 = LDS + 6144, *B1 = LDS + 10240, *B2 = LDS + 14336;
  const int ncol = w * 32;
  const int fr = l & 15, fq = l >> 4;
  f32x4 acc[4][2];
#pragma unroll
  for (int i = 0; i < 4; ++i)
#pragma unroll
    for (int j = 0; j < 2; ++j) acc[i][j] = (f32x4){0.f, 0.f, 0.f, 0.f};
  constexpr int nsteps = E_ / 32;  // 64

  gl2lds16(ga0, A0 + la0);
  gl2lds16(gb0, B0 + lb0); gl2lds16(gb1, B0 + lb1);
  gl2lds16(ga0 + 32, A1 + la0);
  gl2lds16(gb0 + 32, B1 + lb0); gl2lds16(gb1 + 32, B1 + lb1);

  for (int kt = 0; kt < nsteps; ++kt) {
    asm volatile("s_waitcnt vmcnt(3)" ::: "memory");
    __builtin_amdgcn_s_barrier();
    asm volatile("" ::: "memory");
    const int tc = (kt + 2 < nsteps) ? kt + 2 : nsteps - 1;
    gl2lds16(ga0 + tc * 32, A2 + la0);
    gl2lds16(gb0 + tc * 32, B2 + lb0);
    gl2lds16(gb1 + tc * 32, B2 + lb1);
    bf16x8 af[4], bfr[2];
#pragma unroll
    for (int i = 0; i < 4; ++i)
      af[i] = *(const bf16x8*)(A0 + (i * 16 + fr) * 32 + fq * 8);
#pragma unroll
    for (int j = 0; j < 2; ++j)
      bfr[j] = *(const bf16x8*)(B0 + (ncol + j * 16 + fr) * 32 + fq * 8);
#pragma unroll
    for (int i = 0; i < 4; ++i)
#pragma unroll
      for (int j = 0; j < 2; ++j)
        acc[i][j] = __builtin_amdgcn_mfma_f32_16x16x32_bf16(af[i], bfr[j],
                                                            acc[i][j], 0, 0, 0);
    unsigned short* x0 = A0; A0 = A1; A1 = A2; A2 = x0;
    unsigned short* y0 = B0; B0 = B1; B1 = B2; B2 = y0;
  }

  asm volatile("s_waitcnt vmcnt(0) lgkmcnt(0)" ::: "memory");
  __builtin_amdgcn_s_barrier();
  asm volatile("" ::: "memory");

  unsigned short* Xls = LDS;          // [64][128] XOR-swizzled, 16 KiB
  unsigned short* Wls = LDS + 8192;   // [128][128] pre-swizzled, 32 KiB
  {
    const unsigned short* wgsrc = Wsw + w * 4096 + l * 8;
    unsigned short* wldst = Wls + w * 4096;
#pragma unroll
    for (int rr = 0; rr < 8; ++rr)
      gl2lds16(wgsrc + rr * 512, wldst + rr * 512);
  }
  const float* Dvb = Dv + (size_t)b * N_ + n0;
  float sc[4][4];
#pragma unroll
  for (int i = 0; i < 4; ++i)
#pragma unroll
    for (int r = 0; r < 4; ++r)
      sc[i][r] = 1.f / sqrtf(Dvb[i * 16 + fq * 4 + r] + EPS);
#pragma unroll
  for (int i = 0; i < 4; ++i)
#pragma unroll
    for (int j = 0; j < 2; ++j)
#pragma unroll
      for (int r = 0; r < 4; ++r) {
        const int row = i * 16 + fq * 4 + r;
        const int col = ncol + j * 16 + fr;
        Xls[row * 128 + (col ^ ((row & 7) << 3))] = f2bf1(acc[i][j][r] * sc[i][r]);
      }
  asm volatile("s_waitcnt vmcnt(0) lgkmcnt(0)" ::: "memory");
  __builtin_amdgcn_s_barrier();
  asm volatile("" ::: "memory");
  f32x4 a2[4][2];
#pragma unroll
  for (int i = 0; i < 4; ++i)
#pragma unroll
    for (int j = 0; j < 2; ++j) a2[i][j] = (f32x4){0.f, 0.f, 0.f, 0.f};
#pragma unroll
  for (int s = 0; s < 4; ++s) {
    bf16x8 af[4], bfr[2];
#pragma unroll
    for (int i = 0; i < 4; ++i) {
      const int xr = i * 16 + fr;
      af[i] = *(const bf16x8*)(Xls + xr * 128 + ((s * 32 + fq * 8) ^ ((xr & 7) << 3)));
    }
#pragma unroll
    for (int j = 0; j < 2; ++j) {
      const int wr = ncol + j * 16 + fr;
      bfr[j] = *(const bf16x8*)(Wls + wr * 128 + ((s * 32 + fq * 8) ^ ((wr & 7) << 3)));
    }
#pragma unroll
    for (int i = 0; i < 4; ++i)
#pragma unroll
      for (int j = 0; j < 2; ++j)
        a2[i][j] = __builtin_amdgcn_mfma_f32_16x16x32_bf16(af[i], bfr[j],
                                                           a2[i][j], 0, 0, 0);
  }
  float* Ob = out + ((size_t)b * N_ + n0) * 128;
#pragma unroll
  for (int i = 0; i < 4; ++i)
#pragma unroll
    for (int j = 0; j < 2; ++j)
#pragma unroll
      for (int r = 0; r < 4; ++r) {
        const int row = i * 16 + fq * 4 + r;
        const int col = ncol + j * 16 + fr;
        Ob[(size_t)row * 128 + col] = a2[i][j][r] + bias[col];
      }
}

// ---------------------------------------------------------------------------
extern "C" void kernel_launch(void* const* d_in, const int* in_sizes, int n_in,
                              void* d_out, int out_size, void* d_ws, size_t ws_size,
                              hipStream_t stream) {
  const float* x = (const float*)d_in[0];
  const float* H = (const float*)d_in[1];
  const float* W = (const float*)d_in[2];
  const float* bias = (const float*)d_in[3];
  float* out = (float*)d_out;

  unsigned short* Hbf = (unsigned short*)d_ws;          // [B][N][E] bf16, 128MiB
  unsigned short* xsT = Hbf + (size_t)B_ * N_ * E_;     // [B][C][N] bf16, 8MiB
  unsigned short* out2T = xsT + (size_t)B_ * C_ * N_;   // [B][C][E] bf16, 4MiB
  float* P = (float*)(out2T + (size_t)B_ * C_ * E_);    // [4][B][C][E] f32, 32MiB
  unsigned short* Wsw = (unsigned short*)(P + 4 * (size_t)B_ * C_ * E_);  // 32KiB
  float* Pde = (float*)(Wsw + 128 * 128);               // [4][B][16][128] f32
  unsigned int* cnt = (unsigned int*)(Pde + 4 * B_ * 16 * 128);  // [128]
  float* Dv = (float*)(cnt + 128);                      // [B][N]

  k0_prep<<<dim3(16), 256, 0, stream>>>(W, Wsw, cnt);
  k1_fused<<<dim3(B_ * N_ / 64), 256, 0, stream>>>(H, x, Hbf, xsT, Dv);
  gemm1_fused<<<dim3(E_ / 128, 4, B_), 256, 0, stream>>>(Hbf, xsT, P, Pde, cnt,
                                                         out2T);
  gemm2_fused<<<dim3(N_ / 64, 1, B_), 256, 0, stream>>>(Hbf, out2T, Wsw, bias,
                                                        Dv, out);
}